// Round 7
// baseline (369.502 us; speedup 1.0000x reference)
//
#include <hip/hip_runtime.h>
#include <hip/hip_cooperative_groups.h>
#include <math.h>

namespace cg = cooperative_groups;

#define NN 4096
#define DD 256
#define DFF 512
#define HH 8
#define DHH 64
#define CAP_C 256
#define CAP_B 1024

// ws layout (float-element offsets)
#define OFF_KB     0         /* bf16 K [4096][512] */
#define OFF_VB     1048576
#define OFF_QB     2097152
#define OFF_ATTNB  3145728   /* bf16 attn [4096][1024] */
#define OFF_STC    5242880   /* fp32 64*8*4096, layout [a][b] */
#define OFF_STB    7340032   /* fp32 8*8*4096; zero span start */
#define OFF_LSUM   7602176
#define OFF_BSUM   7604224
#define OFF_CNT    7612416   /* 256 ints; zero span end 7612672 */
#define OFF_WQKVT  7612672   /* bf16 Wqkv^T [1536][256] */
#define OFF_WOUTT  7809280   /* bf16 Wout^T [256][1024] */
#define OFF_LISTS  7940352   /* 49152 ints */
#define ZERO_F4    68160     /* (7612672-7340032)/4 float4s */

typedef __attribute__((ext_vector_type(8))) short bf16x8;
typedef __attribute__((ext_vector_type(4))) float floatx4;

__device__ __forceinline__ float gelu_f(float x) {
    const float c = 0.7978845608028654f;
    float t = tanhf(c * (x + 0.044715f * x * x * x));
    return 0.5f * x * (1.0f + t);
}

__device__ __forceinline__ unsigned short f2b(float f) {
    union { float f; unsigned int u; } v; v.f = f;
    unsigned int r = (v.u + 0x7FFFu + ((v.u >> 16) & 1u)) >> 16;
    return (unsigned short)r;
}

__global__ __launch_bounds__(256, 3) void mega_kernel(
    const float* __restrict__ local, const int* __restrict__ chain,
    const int* __restrict__ batch, const int* __restrict__ mask,
    const float* __restrict__ Wk, const float* __restrict__ bk,
    const float* __restrict__ Wv, const float* __restrict__ bv,
    const float* __restrict__ Wq, const float* __restrict__ bq,
    const float* __restrict__ Wbias, const float* __restrict__ bbias,
    const float* __restrict__ Wout, float* __restrict__ out,
    float* __restrict__ ws)
{
    __shared__ __align__(16) char smem[36864];
    const int tid = threadIdx.x;
    cg::grid_group grid = cg::this_grid();

    unsigned short* Kb    = (unsigned short*)(ws + OFF_KB);
    unsigned short* Vb    = (unsigned short*)(ws + OFF_VB);
    unsigned short* Qb    = (unsigned short*)(ws + OFF_QB);
    unsigned short* attnb = (unsigned short*)(ws + OFF_ATTNB);
    float* STc  = ws + OFF_STC;
    float* STb  = ws + OFF_STB;
    float* Lsum = ws + OFF_LSUM;
    float* Bsum = ws + OFF_BSUM;
    int*   cnt  = (int*)(ws + OFF_CNT);
    unsigned short* Wqkvt = (unsigned short*)(ws + OFF_WQKVT);
    unsigned short* Woutt = (unsigned short*)(ws + OFF_WOUTT);
    int* cntc_m   = cnt;
    int* cntc_all = cnt + 64;
    int* cntb_m   = cnt + 128;
    int* cntb_all = cnt + 136;
    int* listc_m   = (int*)(ws + OFF_LISTS);
    int* listc_all = listc_m + 64 * CAP_C;
    int* listb_m   = listc_all + 64 * CAP_C;
    int* listb_all = listb_m + 8 * CAP_B;

    // ---- P0: weight transpose-cast (640) + zero accumulator span (32) ----
    for (int u = blockIdx.x; u < 672; u += gridDim.x) {
        if (u < 640) {
            const float* src; unsigned short* dst; int R, C, r0, c0;
            if (u < 384) {
                int m = u >> 7, ti = u & 127;
                src = (m == 0) ? Wk : (m == 1) ? Wv : Wq;
                dst = Wqkvt + (size_t)m * 512 * 256;
                R = 256; C = 512;
                r0 = (ti >> 4) * 32; c0 = (ti & 15) * 32;
            } else {
                int ti = u - 384;
                src = Wout; dst = Woutt;
                R = 1024; C = 256;
                r0 = (ti >> 3) * 32; c0 = (ti & 7) * 32;
            }
            float (*Tl)[33] = (float(*)[33])smem;
            int ty = tid >> 3, tx = tid & 7;
            float4 v = *(const float4*)(src + (size_t)(r0 + ty) * C + c0 + tx * 4);
            Tl[tx * 4 + 0][ty] = v.x;
            Tl[tx * 4 + 1][ty] = v.y;
            Tl[tx * 4 + 2][ty] = v.z;
            Tl[tx * 4 + 3][ty] = v.w;
            __syncthreads();
            ushort4 o;
            o.x = f2b(Tl[ty][tx * 4 + 0]);
            o.y = f2b(Tl[ty][tx * 4 + 1]);
            o.z = f2b(Tl[ty][tx * 4 + 2]);
            o.w = f2b(Tl[ty][tx * 4 + 3]);
            *(ushort4*)(dst + (size_t)(c0 + ty) * R + r0 + tx * 4) = o;
            __syncthreads();
        } else {
            int z = u - 640;
            float4 z4 = make_float4(0.f, 0.f, 0.f, 0.f);
            float* base = ws + OFF_STB;
            for (int idx = z * 256 + tid; idx < ZERO_F4; idx += 32 * 256)
                *(float4*)(base + (size_t)idx * 4) = z4;
        }
    }
    grid.sync();

    // ---- P1: qkv 128x128 MFMA (384) + list build (16) + direct lsum (16) ----
    for (int u = blockIdx.x; u < 416; u += gridDim.x) {
        if (u < 384) {
            typedef unsigned short (*t72)[72];
            t72 Asl = (t72)smem;
            t72 Bsl = (t72)(smem + 18432);
            const int wave = tid >> 6, lane = tid & 63;
            const int kq = lane >> 4, la = lane & 15;
            const int cx = u % 12, ry = u / 12;
            const int row0 = ry * 128, cg0 = cx * 128;
            const int wrow = (wave & 1) * 64, wcol = (wave >> 1) * 64;

            floatx4 acc[4][4] = {};
            for (int kk = 0; kk < 256; kk += 64) {
#pragma unroll
                for (int t = 0; t < 4; ++t) {
                    int idx = tid + t * 256;
                    int rr = idx >> 3, kc = (idx & 7) * 8;
                    const float* ap = local + (size_t)(row0 + rr) * DD + kk + kc;
                    float4 a0 = *(const float4*)(ap);
                    float4 a1 = *(const float4*)(ap + 4);
                    ushort4 p0, p1;
                    p0.x = f2b(a0.x); p0.y = f2b(a0.y); p0.z = f2b(a0.z); p0.w = f2b(a0.w);
                    p1.x = f2b(a1.x); p1.y = f2b(a1.y); p1.z = f2b(a1.z); p1.w = f2b(a1.w);
                    *(ushort4*)&Asl[rr][kc] = p0;
                    *(ushort4*)&Asl[rr][kc + 4] = p1;
                    *(float4*)&Bsl[rr][kc] =
                        *(const float4*)(Wqkvt + (size_t)(cg0 + rr) * DD + kk + kc);
                }
                __syncthreads();
#pragma unroll
                for (int ks = 0; ks < 2; ++ks) {
                    bf16x8 af[4], bf[4];
#pragma unroll
                    for (int t = 0; t < 4; ++t) {
                        af[t] = *(const bf16x8*)&Asl[wrow + t * 16 + la][ks * 32 + kq * 8];
                        bf[t] = *(const bf16x8*)&Bsl[wcol + t * 16 + la][ks * 32 + kq * 8];
                    }
#pragma unroll
                    for (int at = 0; at < 4; ++at)
#pragma unroll
                        for (int ct = 0; ct < 4; ++ct)
                            acc[at][ct] = __builtin_amdgcn_mfma_f32_16x16x32_bf16(
                                af[at], bf[ct], acc[at][ct], 0, 0, 0);
                }
                __syncthreads();
            }
            const int sel = cg0 >> 9;
            const int do_gelu = (sel != 1);
            const float* bias = (sel == 0) ? bk : (sel == 1) ? bv : bq;
            unsigned short* C = Kb + (size_t)sel * (NN * DFF);
#pragma unroll
            for (int ct = 0; ct < 4; ++ct) {
                int colw = (cg0 + wcol + ct * 16 + la) & 511;
                float bb = bias[colw];
#pragma unroll
                for (int at = 0; at < 4; ++at)
#pragma unroll
                    for (int i = 0; i < 4; ++i) {
                        int row = row0 + wrow + at * 16 + kq * 4 + i;
                        float o = acc[at][ct][i] + bb;
                        if (do_gelu) o = gelu_f(o);
                        C[(size_t)row * DFF + colw] = f2b(o);
                    }
            }
        } else if (u < 400) {
            int* sh = (int*)smem;
            int* hc_m = sh;        int* hc_all = sh + 64;
            int* hb_m = sh + 128;  int* hb_all = sh + 136;
            int* pc_m = sh + 144;  int* pc_all = sh + 208;
            int* pb_m = sh + 272;  int* pb_all = sh + 280;
            if (tid < 64) { hc_m[tid] = 0; hc_all[tid] = 0; }
            if (tid < 8)  { hb_m[tid] = 0; hb_all[tid] = 0; }
            __syncthreads();
            int n = (u - 384) * 256 + tid;
            int c = chain[n], b = batch[n], m = mask[n];
            int rc_all = atomicAdd(&hc_all[c], 1);
            int rb_all = atomicAdd(&hb_all[b], 1);
            int rc_m = -1, rb_m = -1;
            if (m) { rc_m = atomicAdd(&hc_m[c], 1); rb_m = atomicAdd(&hb_m[b], 1); }
            __syncthreads();
            if (tid < 64) {
                pc_all[tid] = atomicAdd(&cntc_all[tid], hc_all[tid]);
                pc_m[tid]   = atomicAdd(&cntc_m[tid],   hc_m[tid]);
            }
            if (tid < 8) {
                pb_all[tid] = atomicAdd(&cntb_all[tid], hb_all[tid]);
                pb_m[tid]   = atomicAdd(&cntb_m[tid],   hb_m[tid]);
            }
            __syncthreads();
            int ia = pc_all[c] + rc_all; if (ia < CAP_C) listc_all[c * CAP_C + ia] = n;
            int ib = pb_all[b] + rb_all; if (ib < CAP_B) listb_all[b * CAP_B + ib] = n;
            if (m) {
                int ja = pc_m[c] + rc_m; if (ja < CAP_C) listc_m[c * CAP_C + ja] = n;
                int jb = pb_m[b] + rb_m; if (jb < CAP_B) listb_m[b * CAP_B + jb] = n;
            }
            __syncthreads();
        } else {
            int i = u - 400;
            float accl[8] = {};
            int n0 = i * 256;
            for (int r = 0; r < 256; ++r) {
                int n = n0 + r;
                float v = local[(size_t)n * DD + tid];
                int bb = batch[n];
                float vm = mask[n] ? v : 0.0f;
#pragma unroll
                for (int b = 0; b < 8; ++b)
                    accl[b] += (bb == b) ? vm : 0.0f;
            }
#pragma unroll
            for (int b = 0; b < 8; ++b)
                atomicAdd(&Lsum[b * DD + tid], accl[b]);
        }
    }
    grid.sync();

    // ---- P2: seg-outer MFMA (1024) + bsum (64) ----
    for (int u = blockIdx.x; u < 1088; u += gridDim.x) {
        if (u >= 1024) {
            int t = u - 1024;
            int seg = t >> 3, kz = t & 7;
            float4 a4 = make_float4(0, 0, 0, 0);
            for (int k = kz * 32; k < kz * 32 + 32; ++k) {
                float l = Lsum[seg * DD + k];
                float4 w = *(const float4*)(Wbias + (size_t)k * 1024 + tid * 4);
                a4.x += l * w.x; a4.y += l * w.y; a4.z += l * w.z; a4.w += l * w.w;
            }
            float* o = Bsum + (size_t)seg * 1024 + tid * 4;
            atomicAdd(o + 0, a4.x); atomicAdd(o + 1, a4.y);
            atomicAdd(o + 2, a4.z); atomicAdd(o + 3, a4.w);
        } else {
            int seg, h, r0, r1, cap;
            const int* list; float* ST; bool direct;
            if (u < 512) {
                seg = u >> 3; h = u & 7;
                cap = CAP_C; list = listc_m; ST = STc;
                r0 = 0; r1 = min(cntc_m[seg], CAP_C); direct = true;
            } else {
                int t = u - 512;
                seg = t >> 6; h = (t >> 3) & 7;
                int z = t & 7;
                cap = CAP_B; list = listb_m; ST = STb;
                int c = min(cntb_m[seg], CAP_B);
                int chunk = (c + 7) / 8;
                r0 = z * chunk; r1 = min(c, r0 + chunk); direct = false;
            }
            typedef unsigned short (*t36)[36];
            t36 Ktl = (t36)smem;
            t36 Vtl = (t36)(smem + 4608);
            const int wave = tid >> 6, lane = tid & 63;
            const int la = lane & 15, kq = lane >> 4;
            floatx4 acc4[4] = {};
            for (int g = r0; g < r1; g += 32) {
#pragma unroll
                for (int it = 0; it < 2; ++it) {
                    int item = tid + it * 256;
                    int nl = item & 31, aq = item >> 5;
                    int gg = g + nl;
                    ushort4 kz4 = make_ushort4(0, 0, 0, 0);
                    ushort4 vz4 = make_ushort4(0, 0, 0, 0);
                    if (gg < r1) {
                        int nn = list[seg * cap + gg];
                        kz4 = *(const ushort4*)(Kb + (size_t)nn * DFF + h * DHH + aq * 4);
                        vz4 = *(const ushort4*)(Vb + (size_t)nn * DFF + h * DHH + aq * 4);
                    }
                    Ktl[aq * 4 + 0][nl] = kz4.x; Ktl[aq * 4 + 1][nl] = kz4.y;
                    Ktl[aq * 4 + 2][nl] = kz4.z; Ktl[aq * 4 + 3][nl] = kz4.w;
                    Vtl[aq * 4 + 0][nl] = vz4.x; Vtl[aq * 4 + 1][nl] = vz4.y;
                    Vtl[aq * 4 + 2][nl] = vz4.z; Vtl[aq * 4 + 3][nl] = vz4.w;
                }
                __syncthreads();
                bf16x8 a = *(const bf16x8*)&Ktl[wave * 16 + la][kq * 8];
#pragma unroll
                for (int bt = 0; bt < 4; ++bt) {
                    bf16x8 b = *(const bf16x8*)&Vtl[bt * 16 + la][kq * 8];
                    acc4[bt] = __builtin_amdgcn_mfma_f32_16x16x32_bf16(a, b, acc4[bt], 0, 0, 0);
                }
                __syncthreads();
            }
            float* outp = ST + (((size_t)seg * HH + h) << 12);
#pragma unroll
            for (int bt = 0; bt < 4; ++bt)
#pragma unroll
                for (int rg = 0; rg < 4; ++rg) {
                    int aa = wave * 16 + kq * 4 + rg;
                    int bb2 = bt * 16 + la;
                    if (direct) outp[aa * 64 + bb2] = acc4[bt][rg];
                    else atomicAdd(&outp[aa * 64 + bb2], acc4[bt][rg]);
                }
        }
    }
    grid.sync();

    // ---- P3: einsum MFMA (1024) ----
    for (int u = blockIdx.x; u < 1024; u += gridDim.x) {
        int seg, h, outoff, cap, r0, r1;
        const float* ST; const int* list; float scaleS;
        if (u < 512) {
            seg = u >> 3; h = u & 7; outoff = 0;
            ST = STc; list = listc_all; cap = CAP_C;
            scaleS = 1.0f / fmaxf((float)cntc_m[seg], 1e-6f);
            r0 = 0; r1 = min(cntc_all[seg], CAP_C);
        } else {
            int t = u - 512;
            seg = t >> 6; h = (t >> 3) & 7;
            int z = t & 7;
            outoff = 64;
            ST = STb; list = listb_all; cap = CAP_B;
            scaleS = 1.0f / fmaxf((float)cntb_m[seg], 1e-6f);
            int c = min(cntb_all[seg], CAP_B);
            int chunk = (c + 7) / 8;
            r0 = z * chunk; r1 = min(c, r0 + chunk);
        }
        typedef unsigned short (*t72)[72];
        t72 Sbl = (t72)smem;
        t72 Qsl = (t72)(smem + 9216);
        float (*Bf)[64] = (float(*)[64])(smem + 18432);
        int* nrow = (int*)(smem + 20480);
        int* nbb  = (int*)(smem + 20736);

        const int wave = tid >> 6, lane = tid & 63;
        const int la = lane & 15, kq = lane >> 4;
        const int colbase = h * 128 + outoff;

        const float* Sg = ST + (((size_t)seg * HH + h) << 12);
#pragma unroll
        for (int i = 0; i < 4; ++i) {
            int e = tid + i * 256;
            float4 v = *(const float4*)(Sg + (size_t)e * 4);
            int a = e >> 4, b = (e & 15) * 4;
            ushort4 o;
            o.x = f2b(v.x * scaleS); o.y = f2b(v.y * scaleS);
            o.z = f2b(v.z * scaleS); o.w = f2b(v.w * scaleS);
            *(ushort4*)&Sbl[a][b] = o;
        }
#pragma unroll
        for (int e = tid; e < 512; e += 256) {
            int bbq = e >> 6, j = e & 63;
            float cm = (float)cntb_m[bbq];
            float inv = 1.0f / fmaxf(cm, 1e-6f);
            int col = colbase + j;
            Bf[bbq][j] = (Bsum[(size_t)bbq * 1024 + col] + cm * bbias[col]) * inv;
        }
        __syncthreads();

        for (int g = r0; g < r1; g += 64) {
            if (tid < 64) {
                int gg = g + tid;
                int n = (gg < r1) ? list[seg * cap + gg] : -1;
                nrow[tid] = n;
                nbb[tid] = (n >= 0) ? batch[n] : 0;
            }
            __syncthreads();
            {
                int row = tid & 63, pr = tid >> 6;
                int n = nrow[row];
                if (n >= 0) {
#pragma unroll
                    for (int it = 0; it < 2; ++it) {
                        int off = (pr + it * 4) * 8;
                        *(float4*)&Qsl[row][off] =
                            *(const float4*)(Qb + (size_t)n * DFF + h * DHH + off);
                    }
                }
            }
            __syncthreads();

            floatx4 acc[4] = {};
#pragma unroll
            for (int ks = 0; ks < 2; ++ks) {
                bf16x8 a = *(const bf16x8*)&Qsl[wave * 16 + la][ks * 32 + kq * 8];
#pragma unroll
                for (int ct = 0; ct < 4; ++ct) {
                    bf16x8 b = *(const bf16x8*)&Sbl[ct * 16 + la][ks * 32 + kq * 8];
                    acc[ct] = __builtin_amdgcn_mfma_f32_16x16x32_bf16(a, b, acc[ct], 0, 0, 0);
                }
            }
#pragma unroll
            for (int ct = 0; ct < 4; ++ct)
#pragma unroll
                for (int rg = 0; rg < 4; ++rg) {
                    int rowl = wave * 16 + kq * 4 + rg;
                    float bias = Bf[nbb[rowl]][ct * 16 + la];
                    Qsl[rowl][ct * 16 + la] = f2b(acc[ct][rg] + bias);
                }
            __syncthreads();
            {
                int row = tid & 63, pr = tid >> 6;
                int n = nrow[row];
                if (n >= 0) {
#pragma unroll
                    for (int it = 0; it < 2; ++it) {
                        int off = (pr + it * 4) * 8;
                        *(float4*)(attnb + (size_t)n * 1024 + colbase + off) =
                            *(const float4*)&Qsl[row][off];
                    }
                }
            }
            __syncthreads();
        }
    }
    grid.sync();

    // ---- P4: final GEMM (512) ----
    for (int u = blockIdx.x; u < 512; u += gridDim.x) {
        const int K = 1024;
        typedef unsigned short (*t136)[136];
        t136 Asl = (t136)smem;
        t136 Bsl = (t136)(smem + 8704);
        const int wave = tid >> 6, lane = tid & 63;
        const int q = lane >> 4, r = lane & 15;
        const int row0 = (u >> 2) * 32, cg0 = (u & 3) * 64;
        const int wrow = (wave & 1) * 16, wcol = (wave >> 1) * 32;

        floatx4 acc[2] = {};
        for (int kk = 0; kk < K; kk += 128) {
#pragma unroll
            for (int t = 0; t < 2; ++t) {
                int idx = tid + t * 256;
                int rr = idx >> 4, kc = (idx & 15) * 8;
                *(float4*)&Asl[rr][kc] =
                    *(const float4*)(attnb + (size_t)(row0 + rr) * K + kk + kc);
            }
#pragma unroll
            for (int t = 0; t < 4; ++t) {
                int idx = tid + t * 256;
                int rr = idx >> 4, kc = (idx & 15) * 8;
                *(float4*)&Bsl[rr][kc] =
                    *(const float4*)(Woutt + (size_t)(cg0 + rr) * K + kk + kc);
            }
            __syncthreads();
#pragma unroll
            for (int sub = 0; sub < 4; ++sub) {
                bf16x8 a = *(const bf16x8*)&Asl[wrow + r][sub * 32 + q * 8];
#pragma unroll
                for (int c = 0; c < 2; ++c) {
                    bf16x8 b = *(const bf16x8*)&Bsl[wcol + c * 16 + r][sub * 32 + q * 8];
                    acc[c] = __builtin_amdgcn_mfma_f32_16x16x32_bf16(a, b, acc[c], 0, 0, 0);
                }
            }
            __syncthreads();
        }
#pragma unroll
        for (int c = 0; c < 2; ++c) {
            int col = cg0 + wcol + c * 16 + r;
#pragma unroll
            for (int i = 0; i < 4; ++i) {
                int row = row0 + wrow + q * 4 + i;
                out[(size_t)row * DD + col] = acc[c][i];
            }
        }
    }
}

extern "C" void kernel_launch(void* const* d_in, const int* in_sizes, int n_in,
                              void* d_out, int out_size, void* d_ws, size_t ws_size,
                              hipStream_t stream)
{
    const float* local   = (const float*)d_in[0];
    const int*   chain   = (const int*)d_in[1];
    const int*   batch   = (const int*)d_in[2];
    const int*   mask    = (const int*)d_in[3];
    const float* W_key   = (const float*)d_in[4];
    const float* b_key   = (const float*)d_in[5];
    const float* W_value = (const float*)d_in[6];
    const float* b_value = (const float*)d_in[7];
    const float* W_query = (const float*)d_in[8];
    const float* b_query = (const float*)d_in[9];
    const float* W_bias  = (const float*)d_in[10];
    const float* b_bias  = (const float*)d_in[11];
    const float* W_out   = (const float*)d_in[12];
    float* out = (float*)d_out;
    float* ws  = (float*)d_ws;

    int occ = 0;
    if (hipOccupancyMaxActiveBlocksPerMultiprocessor(&occ, mega_kernel, 256, 0) != hipSuccess || occ < 1)
        occ = 1;
    int grid = occ * 256;
    if (grid > 768) grid = 768;

    void* kargs[] = {
        (void*)&local, (void*)&chain, (void*)&batch, (void*)&mask,
        (void*)&W_key, (void*)&b_key, (void*)&W_value, (void*)&b_value,
        (void*)&W_query, (void*)&b_query, (void*)&W_bias, (void*)&b_bias,
        (void*)&W_out, (void*)&out, (void*)&ws };
    hipLaunchCooperativeKernel((void*)mega_kernel, dim3(grid), dim3(256), kargs, 0, stream);
}

// Round 8
// 151.628 us; speedup vs baseline: 2.4369x; 2.4369x over previous
//
#include <hip/hip_runtime.h>
#include <math.h>

#define NN 4096
#define DD 256
#define DFF 512
#define HH 8
#define DHH 64
#define CAP_C 256
#define CAP_B 1024

// ws layout (float-element offsets)
#define OFF_KB     0         /* bf16 K [4096][512] */
#define OFF_VB     1048576
#define OFF_QB     2097152
#define OFF_ATTNB  3145728   /* bf16 attn [4096][1024] */
#define OFF_STC    5242880   /* fp32 64*8*4096, [a][b] */
#define OFF_STB    7340032   /* fp32 8*8*4096, [a][b] (direct store, no zero) */
#define OFF_BSUM   7602176   /* fp32 8*1024  — zeroed in prep */
#define OFF_CNT    7610368   /* 256 ints     — zeroed in prep */
#define OFF_WQKVT  7610624   /* bf16 Wqkv^T [1536][256] */
#define OFF_WOUTT  7807232   /* bf16 Wout^T [256][1024] */
#define OFF_LISTS  7938304   /* 49152 ints */
#define OFF_LPART  7987456   /* fp32 [64][8][256] */

typedef __attribute__((ext_vector_type(8))) short bf16x8;
typedef __attribute__((ext_vector_type(4))) float floatx4;

__device__ __forceinline__ float gelu_f(float x) {
    const float c = 0.7978845608028654f;
    float t = tanhf(c * (x + 0.044715f * x * x * x));
    return 0.5f * x * (1.0f + t);
}

__device__ __forceinline__ unsigned short f2b(float f) {
    union { float f; unsigned int u; } v; v.f = f;
    unsigned int r = (v.u + 0x7FFFu + ((v.u >> 16) & 1u)) >> 16;
    return (unsigned short)r;
}

// ---------------------------------------------------------------------------
// prep: [0,640) weight transpose-cast; [640,704) Lpart partial batch sums
// (list-free, no atomics); [704] zero Bsum+cnt.
// ---------------------------------------------------------------------------
__global__ __launch_bounds__(256) void prep_kernel(
    const float* __restrict__ local,
    const float* __restrict__ Wk, const float* __restrict__ Wv,
    const float* __restrict__ Wq, const float* __restrict__ Wout,
    const int* __restrict__ batch, const int* __restrict__ mask,
    unsigned short* __restrict__ Wqkvt, unsigned short* __restrict__ Woutt,
    float* __restrict__ Lpart, float* __restrict__ zero_base)
{
    const int bid = blockIdx.x, tid = threadIdx.x;
    if (bid < 640) {
        const float* src; unsigned short* dst; int R, C, r0, c0;
        if (bid < 384) {
            int m = bid >> 7, ti = bid & 127;
            src = (m == 0) ? Wk : (m == 1) ? Wv : Wq;
            dst = Wqkvt + (size_t)m * 512 * 256;
            R = 256; C = 512;
            r0 = (ti >> 4) * 32; c0 = (ti & 15) * 32;
        } else {
            int ti = bid - 384;
            src = Wout; dst = Woutt;
            R = 1024; C = 256;
            r0 = (ti >> 3) * 32; c0 = (ti & 7) * 32;
        }
        __shared__ float Tl[32][33];
        int ty = tid >> 3, tx = tid & 7;
        float4 v = *(const float4*)(src + (size_t)(r0 + ty) * C + c0 + tx * 4);
        Tl[tx * 4 + 0][ty] = v.x;
        Tl[tx * 4 + 1][ty] = v.y;
        Tl[tx * 4 + 2][ty] = v.z;
        Tl[tx * 4 + 3][ty] = v.w;
        __syncthreads();
        ushort4 o;
        o.x = f2b(Tl[ty][tx * 4 + 0]);
        o.y = f2b(Tl[ty][tx * 4 + 1]);
        o.z = f2b(Tl[ty][tx * 4 + 2]);
        o.w = f2b(Tl[ty][tx * 4 + 3]);
        *(ushort4*)(dst + (size_t)(c0 + ty) * R + r0 + tx * 4) = o;
    } else if (bid < 704) {
        int p = bid - 640;
        float accl[8] = {};
        int n0 = p * 64;
        for (int r = 0; r < 64; ++r) {
            int n = n0 + r;
            float v = local[(size_t)n * DD + tid];
            int bb = batch[n];
            float vm = mask[n] ? v : 0.0f;
#pragma unroll
            for (int b = 0; b < 8; ++b)
                accl[b] += (bb == b) ? vm : 0.0f;
        }
#pragma unroll
        for (int b = 0; b < 8; ++b)
            Lpart[(size_t)p * 2048 + b * 256 + tid] = accl[b];
    } else {
        float4 z4 = make_float4(0.f, 0.f, 0.f, 0.f);
        for (int i = tid; i < 2112; i += 256)   // 8448 floats (Bsum + cnt)
            ((float4*)zero_base)[i] = z4;
    }
}

// ---------------------------------------------------------------------------
// qkv dispatch, flat grid 464:
//  u < 384: 128x128 MFMA GEMM (A = local, cast fp32->bf16 during staging)
//  u < 400: segment list build (LDS-aggregated atomics)
//  u < 464: bsum (reduce Lpart -> Lk in LDS, then Lk @ Wbias slice)
// ---------------------------------------------------------------------------
__global__ __launch_bounds__(256) void qkv_kernel(
    const float* __restrict__ local, const unsigned short* __restrict__ Wqkvt,
    const float* __restrict__ bk, const float* __restrict__ bv,
    const float* __restrict__ bq, unsigned short* __restrict__ KVQb,
    const int* __restrict__ chain, const int* __restrict__ batch,
    const int* __restrict__ mask, int* __restrict__ cnt,
    int* __restrict__ lists, const float* __restrict__ Lpart,
    const float* __restrict__ Wbias, float* __restrict__ Bsum)
{
    __shared__ __align__(16) char smem[36864];
    const int u = blockIdx.x, tid = threadIdx.x;
    int* cntc_m   = cnt;
    int* cntc_all = cnt + 64;
    int* cntb_m   = cnt + 128;
    int* cntb_all = cnt + 136;
    int* listc_m   = lists;
    int* listc_all = listc_m + 64 * CAP_C;
    int* listb_m   = listc_all + 64 * CAP_C;
    int* listb_all = listb_m + 8 * CAP_B;

    if (u < 384) {
        typedef unsigned short (*t72)[72];
        t72 Asl = (t72)smem;
        t72 Bsl = (t72)(smem + 18432);
        const int wave = tid >> 6, lane = tid & 63;
        const int kq = lane >> 4, la = lane & 15;
        const int cx = u % 12, ry = u / 12;
        const int row0 = ry * 128, cg0 = cx * 128;
        const int wrow = (wave & 1) * 64, wcol = (wave >> 1) * 64;

        floatx4 acc[4][4] = {};
        for (int kk = 0; kk < 256; kk += 64) {
#pragma unroll
            for (int t = 0; t < 4; ++t) {
                int idx = tid + t * 256;
                int rr = idx >> 3, kc = (idx & 7) * 8;
                const float* ap = local + (size_t)(row0 + rr) * DD + kk + kc;
                float4 a0 = *(const float4*)(ap);
                float4 a1 = *(const float4*)(ap + 4);
                ushort4 p0, p1;
                p0.x = f2b(a0.x); p0.y = f2b(a0.y); p0.z = f2b(a0.z); p0.w = f2b(a0.w);
                p1.x = f2b(a1.x); p1.y = f2b(a1.y); p1.z = f2b(a1.z); p1.w = f2b(a1.w);
                *(ushort4*)&Asl[rr][kc] = p0;
                *(ushort4*)&Asl[rr][kc + 4] = p1;
                *(float4*)&Bsl[rr][kc] =
                    *(const float4*)(Wqkvt + (size_t)(cg0 + rr) * DD + kk + kc);
            }
            __syncthreads();
#pragma unroll
            for (int ks = 0; ks < 2; ++ks) {
                bf16x8 af[4], bf[4];
#pragma unroll
                for (int t = 0; t < 4; ++t) {
                    af[t] = *(const bf16x8*)&Asl[wrow + t * 16 + la][ks * 32 + kq * 8];
                    bf[t] = *(const bf16x8*)&Bsl[wcol + t * 16 + la][ks * 32 + kq * 8];
                }
#pragma unroll
                for (int at = 0; at < 4; ++at)
#pragma unroll
                    for (int ct = 0; ct < 4; ++ct)
                        acc[at][ct] = __builtin_amdgcn_mfma_f32_16x16x32_bf16(
                            af[at], bf[ct], acc[at][ct], 0, 0, 0);
            }
            __syncthreads();
        }
        const int sel = cg0 >> 9;
        const int do_gelu = (sel != 1);
        const float* bias = (sel == 0) ? bk : (sel == 1) ? bv : bq;
        unsigned short* C = KVQb + (size_t)sel * (NN * DFF);
#pragma unroll
        for (int ct = 0; ct < 4; ++ct) {
            int colw = (cg0 + wcol + ct * 16 + la) & 511;
            float bb = bias[colw];
#pragma unroll
            for (int at = 0; at < 4; ++at)
#pragma unroll
                for (int i = 0; i < 4; ++i) {
                    int row = row0 + wrow + at * 16 + kq * 4 + i;
                    float o = acc[at][ct][i] + bb;
                    if (do_gelu) o = gelu_f(o);
                    C[(size_t)row * DFF + colw] = f2b(o);
                }
        }
    } else if (u < 400) {
        int* sh = (int*)smem;
        int* hc_m = sh;        int* hc_all = sh + 64;
        int* hb_m = sh + 128;  int* hb_all = sh + 136;
        int* pc_m = sh + 144;  int* pc_all = sh + 208;
        int* pb_m = sh + 272;  int* pb_all = sh + 280;
        if (tid < 64) { hc_m[tid] = 0; hc_all[tid] = 0; }
        if (tid < 8)  { hb_m[tid] = 0; hb_all[tid] = 0; }
        __syncthreads();
        int n = (u - 384) * 256 + tid;
        int c = chain[n], b = batch[n], m = mask[n];
        int rc_all = atomicAdd(&hc_all[c], 1);
        int rb_all = atomicAdd(&hb_all[b], 1);
        int rc_m = -1, rb_m = -1;
        if (m) { rc_m = atomicAdd(&hc_m[c], 1); rb_m = atomicAdd(&hb_m[b], 1); }
        __syncthreads();
        if (tid < 64) {
            pc_all[tid] = atomicAdd(&cntc_all[tid], hc_all[tid]);
            pc_m[tid]   = atomicAdd(&cntc_m[tid],   hc_m[tid]);
        }
        if (tid < 8) {
            pb_all[tid] = atomicAdd(&cntb_all[tid], hb_all[tid]);
            pb_m[tid]   = atomicAdd(&cntb_m[tid],   hb_m[tid]);
        }
        __syncthreads();
        int ia = pc_all[c] + rc_all; if (ia < CAP_C) listc_all[c * CAP_C + ia] = n;
        int ib = pb_all[b] + rb_all; if (ib < CAP_B) listb_all[b * CAP_B + ib] = n;
        if (m) {
            int ja = pc_m[c] + rc_m; if (ja < CAP_C) listc_m[c * CAP_C + ja] = n;
            int jb = pb_m[b] + rb_m; if (jb < CAP_B) listb_m[b * CAP_B + jb] = n;
        }
    } else {
        int t = u - 400;                 // 0..63
        const int seg = t >> 3, kz = t & 7;
        float (*Ltmp)[32] = (float(*)[32])smem;     // 64x32 fp32 = 8 KB
        float* Lk = (float*)(smem + 8192);          // 32 fp32
        for (int idx = tid; idx < 2048; idx += 256) {
            int p = idx >> 5, k = idx & 31;
            Ltmp[p][k] = Lpart[(size_t)p * 2048 + seg * 256 + kz * 32 + k];
        }
        __syncthreads();
        if (tid < 32) {
            float s = 0.0f;
            for (int p = 0; p < 64; ++p) s += Ltmp[p][tid];
            Lk[tid] = s;
        }
        __syncthreads();
        float4 a4 = make_float4(0, 0, 0, 0);
        for (int k = 0; k < 32; ++k) {
            float l = Lk[k];
            float4 w = *(const float4*)(Wbias + (size_t)(kz * 32 + k) * 1024 + tid * 4);
            a4.x += l * w.x; a4.y += l * w.y; a4.z += l * w.z; a4.w += l * w.w;
        }
        float* o = Bsum + (size_t)seg * 1024 + tid * 4;
        atomicAdd(o + 0, a4.x); atomicAdd(o + 1, a4.y);
        atomicAdd(o + 2, a4.z); atomicAdd(o + 3, a4.w);
    }
}

// ---------------------------------------------------------------------------
// mid: seg-outer MFMA, flat grid 576, ALL direct store (no atomics, no zero):
//  u < 512: chain (seg=u>>3, h=u&7); else batch (t=u-512: seg=t>>3, h=t&7).
// ---------------------------------------------------------------------------
__global__ __launch_bounds__(256) void mid_kernel(
    const unsigned short* __restrict__ Kb, const unsigned short* __restrict__ Vb,
    const int* __restrict__ listc_m, const int* __restrict__ cntc_m,
    float* __restrict__ STc,
    const int* __restrict__ listb_m, const int* __restrict__ cntb_m,
    float* __restrict__ STb)
{
    const int u = blockIdx.x, tid = threadIdx.x;
    int seg, h, r1, cap;
    const int* list; float* ST;
    if (u < 512) {
        seg = u >> 3; h = u & 7;
        cap = CAP_C; list = listc_m; ST = STc;
        r1 = min(cntc_m[seg], CAP_C);
    } else {
        int t = u - 512;
        seg = t >> 3; h = t & 7;
        cap = CAP_B; list = listb_m; ST = STb;
        r1 = min(cntb_m[seg], CAP_B);
    }

    __shared__ unsigned short Ktl[64][36];
    __shared__ unsigned short Vtl[64][36];
    const int wave = tid >> 6, lane = tid & 63;
    const int la = lane & 15, kq = lane >> 4;

    floatx4 acc4[4] = {};
    for (int g = 0; g < r1; g += 32) {
#pragma unroll
        for (int it = 0; it < 2; ++it) {
            int item = tid + it * 256;
            int nl = item & 31, aq = item >> 5;
            int gg = g + nl;
            ushort4 kz4 = make_ushort4(0, 0, 0, 0);
            ushort4 vz4 = make_ushort4(0, 0, 0, 0);
            if (gg < r1) {
                int nn = list[seg * cap + gg];
                kz4 = *(const ushort4*)(Kb + (size_t)nn * DFF + h * DHH + aq * 4);
                vz4 = *(const ushort4*)(Vb + (size_t)nn * DFF + h * DHH + aq * 4);
            }
            Ktl[aq * 4 + 0][nl] = kz4.x; Ktl[aq * 4 + 1][nl] = kz4.y;
            Ktl[aq * 4 + 2][nl] = kz4.z; Ktl[aq * 4 + 3][nl] = kz4.w;
            Vtl[aq * 4 + 0][nl] = vz4.x; Vtl[aq * 4 + 1][nl] = vz4.y;
            Vtl[aq * 4 + 2][nl] = vz4.z; Vtl[aq * 4 + 3][nl] = vz4.w;
        }
        __syncthreads();
        bf16x8 a = *(const bf16x8*)&Ktl[wave * 16 + la][kq * 8];
#pragma unroll
        for (int bt = 0; bt < 4; ++bt) {
            bf16x8 b = *(const bf16x8*)&Vtl[bt * 16 + la][kq * 8];
            acc4[bt] = __builtin_amdgcn_mfma_f32_16x16x32_bf16(a, b, acc4[bt], 0, 0, 0);
        }
        __syncthreads();
    }

    float* outp = ST + (((size_t)seg * HH + h) << 12);
#pragma unroll
    for (int bt = 0; bt < 4; ++bt)
#pragma unroll
        for (int rg = 0; rg < 4; ++rg) {
            int aa = wave * 16 + kq * 4 + rg;
            int bb2 = bt * 16 + la;
            outp[aa * 64 + bb2] = acc4[bt][rg];
        }
}

// ---------------------------------------------------------------------------
// einsum (MFMA), flat grid 1024: id<512 chain (outoff 0), else batch
// (outoff 64, z=8). out[n,a] = sum_b S[a][b]*scale * q[n,b] + biasTable.
// ---------------------------------------------------------------------------
__global__ __launch_bounds__(256) void einsum_kernel(
    const float* __restrict__ STc, const int* __restrict__ cntc_m,
    const int* __restrict__ listc_all, const int* __restrict__ cntc_all,
    const float* __restrict__ STb, const int* __restrict__ cntb_m,
    const int* __restrict__ listb_all, const int* __restrict__ cntb_all,
    const unsigned short* __restrict__ Qb, const int* __restrict__ batch,
    const float* __restrict__ Bsum, const float* __restrict__ b_bias,
    unsigned short* __restrict__ attnb)
{
    const int id = blockIdx.x, tid = threadIdx.x;
    int seg, h, outoff, cap, r0, r1;
    const float* ST;
    const int* list;
    float scaleS;
    if (id < 512) {
        seg = id >> 3; h = id & 7; outoff = 0;
        ST = STc; list = listc_all; cap = CAP_C;
        scaleS = 1.0f / fmaxf((float)cntc_m[seg], 1e-6f);
        r0 = 0; r1 = min(cntc_all[seg], CAP_C);
    } else {
        int t = id - 512;
        seg = t >> 6; h = (t >> 3) & 7;
        int z = t & 7;
        outoff = 64;
        ST = STb; list = listb_all; cap = CAP_B;
        scaleS = 1.0f / fmaxf((float)cntb_m[seg], 1e-6f);
        int c = min(cntb_all[seg], CAP_B);
        int chunk = (c + 7) / 8;
        r0 = z * chunk; r1 = min(c, r0 + chunk);
    }

    __shared__ unsigned short Sbl[64][72];
    __shared__ unsigned short Qsl[64][72];
    __shared__ float Bf[8][64];
    __shared__ int nrow[64];
    __shared__ int nbb[64];

    const int wave = tid >> 6, lane = tid & 63;
    const int la = lane & 15, kq = lane >> 4;
    const int colbase = h * 128 + outoff;

    const float* Sg = ST + (((size_t)seg * HH + h) << 12);
#pragma unroll
    for (int i = 0; i < 4; ++i) {
        int e = tid + i * 256;
        float4 v = *(const float4*)(Sg + (size_t)e * 4);
        int a = e >> 4, b = (e & 15) * 4;
        ushort4 o;
        o.x = f2b(v.x * scaleS); o.y = f2b(v.y * scaleS);
        o.z = f2b(v.z * scaleS); o.w = f2b(v.w * scaleS);
        *(ushort4*)&Sbl[a][b] = o;
    }
#pragma unroll
    for (int e = tid; e < 512; e += 256) {
        int bbq = e >> 6, j = e & 63;
        float cm = (float)cntb_m[bbq];
        float inv = 1.0f / fmaxf(cm, 1e-6f);
        int col = colbase + j;
        Bf[bbq][j] = (Bsum[(size_t)bbq * 1024 + col] + cm * b_bias[col]) * inv;
    }
    __syncthreads();

    for (int g = r0; g < r1; g += 64) {
        if (tid < 64) {
            int gg = g + tid;
            int n = (gg < r1) ? list[seg * cap + gg] : -1;
            nrow[tid] = n;
            nbb[tid] = (n >= 0) ? batch[n] : 0;
        }
        __syncthreads();
        {
            int row = tid & 63, pr = tid >> 6;
            int n = nrow[row];
            if (n >= 0) {
#pragma unroll
                for (int it = 0; it < 2; ++it) {
                    int off = (pr + it * 4) * 8;
                    *(float4*)&Qsl[row][off] =
                        *(const float4*)(Qb + (size_t)n * DFF + h * DHH + off);
                }
            }
        }
        __syncthreads();

        floatx4 acc[4] = {};
#pragma unroll
        for (int ks = 0; ks < 2; ++ks) {
            bf16x8 a = *(const bf16x8*)&Qsl[wave * 16 + la][ks * 32 + kq * 8];
#pragma unroll
            for (int ct = 0; ct < 4; ++ct) {
                bf16x8 b = *(const bf16x8*)&Sbl[ct * 16 + la][ks * 32 + kq * 8];
                acc[ct] = __builtin_amdgcn_mfma_f32_16x16x32_bf16(a, b, acc[ct], 0, 0, 0);
            }
        }
#pragma unroll
        for (int ct = 0; ct < 4; ++ct)
#pragma unroll
            for (int rg = 0; rg < 4; ++rg) {
                int rowl = wave * 16 + kq * 4 + rg;
                float bias = Bf[nbb[rowl]][ct * 16 + la];
                Qsl[rowl][ct * 16 + la] = f2b(acc[ct][rg] + bias);
            }
        __syncthreads();
        {
            int row = tid & 63, pr = tid >> 6;
            int n = nrow[row];
            if (n >= 0) {
#pragma unroll
                for (int it = 0; it < 2; ++it) {
                    int off = (pr + it * 4) * 8;
                    *(float4*)(attnb + (size_t)n * 1024 + colbase + off) =
                        *(const float4*)&Qsl[row][off];
                }
            }
        }
        __syncthreads();
    }
}

// ---------------------------------------------------------------------------
// Final GEMM: out = attnb @ W_out. 32x64 tile, BK=128 (8 iters), grid (4,128).
// ---------------------------------------------------------------------------
__global__ __launch_bounds__(256) void mfma_gemm_final(
    const unsigned short* __restrict__ A, const unsigned short* __restrict__ Bt,
    float* __restrict__ out)
{
    const int K = 1024;
    __shared__ unsigned short Asl[32][136];
    __shared__ unsigned short Bsl[64][136];
    const int tid = threadIdx.x;
    const int wave = tid >> 6, lane = tid & 63;
    const int q = lane >> 4, r = lane & 15;
    const int row0 = blockIdx.y * 32, cg0 = blockIdx.x * 64;
    const int wrow = (wave & 1) * 16, wcol = (wave >> 1) * 32;

    floatx4 acc[2] = {};
    for (int kk = 0; kk < K; kk += 128) {
#pragma unroll
        for (int t = 0; t < 2; ++t) {
            int idx = tid + t * 256;
            int rr = idx >> 4, kc = (idx & 15) * 8;
            *(float4*)&Asl[rr][kc] = *(const float4*)(A + (size_t)(row0 + rr) * K + kk + kc);
        }
#pragma unroll
        for (int t = 0; t < 4; ++t) {
            int idx = tid + t * 256;
            int rr = idx >> 4, kc = (idx & 15) * 8;
            *(float4*)&Bsl[rr][kc] = *(const float4*)(Bt + (size_t)(cg0 + rr) * K + kk + kc);
        }
        __syncthreads();
#pragma unroll
        for (int sub = 0; sub < 4; ++sub) {
            bf16x8 a = *(const bf16x8*)&Asl[wrow + r][sub * 32 + q * 8];
#pragma unroll
            for (int c = 0; c < 2; ++c) {
                bf16x8 b = *(const bf16x8*)&Bsl[wcol + c * 16 + r][sub * 32 + q * 8];
                acc[c] = __builtin_amdgcn_mfma_f32_16x16x32_bf16(a, b, acc[c], 0, 0, 0);
            }
        }
        __syncthreads();
    }
#pragma unroll
    for (int c = 0; c < 2; ++c) {
        int col = cg0 + wcol + c * 16 + r;
#pragma unroll
        for (int i = 0; i < 4; ++i) {
            int row = row0 + wrow + q * 4 + i;
            out[(size_t)row * DD + col] = acc[c][i];
        }
    }
}

extern "C" void kernel_launch(void* const* d_in, const int* in_sizes, int n_in,
                              void* d_out, int out_size, void* d_ws, size_t ws_size,
                              hipStream_t stream)
{
    const float* local   = (const float*)d_in[0];
    const int*   chain   = (const int*)d_in[1];
    const int*   batch   = (const int*)d_in[2];
    const int*   mask    = (const int*)d_in[3];
    const float* W_key   = (const float*)d_in[4];
    const float* b_key   = (const float*)d_in[5];
    const float* W_value = (const float*)d_in[6];
    const float* b_value = (const float*)d_in[7];
    const float* W_query = (const float*)d_in[8];
    const float* b_query = (const float*)d_in[9];
    const float* W_bias  = (const float*)d_in[10];
    const float* b_bias  = (const float*)d_in[11];
    const float* W_out   = (const float*)d_in[12];
    float* out = (float*)d_out;

    float* ws = (float*)d_ws;
    unsigned short* Kb    = (unsigned short*)(ws + OFF_KB);
    unsigned short* Vb    = (unsigned short*)(ws + OFF_VB);
    unsigned short* Qb    = (unsigned short*)(ws + OFF_QB);
    unsigned short* attnb = (unsigned short*)(ws + OFF_ATTNB);
    float* STc    = ws + OFF_STC;
    float* STb    = ws + OFF_STB;
    float* Bsum   = ws + OFF_BSUM;
    int*   cnt    = (int*)(ws + OFF_CNT);
    unsigned short* Wqkvt = (unsigned short*)(ws + OFF_WQKVT);
    unsigned short* Woutt = (unsigned short*)(ws + OFF_WOUTT);
    int*   lists  = (int*)(ws + OFF_LISTS);
    float* Lpart  = ws + OFF_LPART;
    int* cntc_m   = cnt;
    int* cntb_m   = cnt + 128;
    int* cntc_all = cnt + 64;
    int* cntb_all = cnt + 136;
    int* listc_m   = lists;
    int* listc_all = listc_m + 64 * CAP_C;
    int* listb_m   = listc_all + 64 * CAP_C;
    int* listb_all = listb_m + 8 * CAP_B;

    dim3 blk(256);

    prep_kernel<<<dim3(705), blk, 0, stream>>>(
        local, W_key, W_value, W_query, W_out, batch, mask,
        Wqkvt, Woutt, Lpart, ws + OFF_BSUM);

    qkv_kernel<<<dim3(464), blk, 0, stream>>>(
        local, Wqkvt, b_key, b_value, b_query, Kb,
        chain, batch, mask, cnt, lists, Lpart, W_bias, Bsum);

    mid_kernel<<<dim3(576), blk, 0, stream>>>(
        Kb, Vb, listc_m, cntc_m, STc, listb_m, cntb_m, STb);

    einsum_kernel<<<dim3(1024), blk, 0, stream>>>(
        STc, cntc_m, listc_all, cntc_all, STb, cntb_m, listb_all, cntb_all,
        Qb, batch, Bsum, b_bias, attnb);

    mfma_gemm_final<<<dim3(4, 128), blk, 0, stream>>>(attnb, Woutt, out);
}